// Round 2
// baseline (87372.284 us; speedup 1.0000x reference)
//
#include <hip/hip_runtime.h>

#define T_STEPS 8192
#define F_IN 64
#define R_DIM 2048
#define G_BLK 256
#define ROWS_PER_BLK 8   // R_DIM / G_BLK
#define LR 0.9f

// Padded LDS index for x: +4 floats per 64 -> spreads the stride-256B
// ds_read_b128 fan-out across bank groups (<=4-way conflict instead of 32-way).
__device__ __forceinline__ int xidx(int c) { return c + ((c >> 6) << 2); }

// ---------------- proj = u_in @ Win^T + b  (one-time, written into d_out) ----
__global__ __launch_bounds__(256) void esn_proj_kernel(
    const float* __restrict__ u, const float* __restrict__ Winw,
    const float* __restrict__ Winb, float* __restrict__ proj)
{
    __shared__ float u_s[64 * F_IN];                  // 64 timesteps x 64 features
    const int t0 = blockIdx.x * 64;
    const int r  = blockIdx.y * 256 + threadIdx.x;

    const float4* usrc = (const float4*)(u + (size_t)t0 * F_IN);
    float4* udst = (float4*)u_s;
#pragma unroll
    for (int i = 0; i < 4; ++i)
        udst[threadIdx.x + 256 * i] = usrc[threadIdx.x + 256 * i];
    __syncthreads();

    float w[F_IN];
    const float4* wrow = (const float4*)(Winw + (size_t)r * F_IN);
#pragma unroll
    for (int k = 0; k < F_IN / 4; ++k) {
        float4 v = wrow[k];
        w[4*k] = v.x; w[4*k+1] = v.y; w[4*k+2] = v.z; w[4*k+3] = v.w;
    }
    const float bias = Winb[r];

    for (int tt = 0; tt < 64; ++tt) {
        const float4* ur = (const float4*)(u_s + tt * F_IN);  // wave-uniform: broadcast
        float acc = bias;
#pragma unroll
        for (int k = 0; k < F_IN / 4; ++k) {
            float4 uv = ur[k];
            acc += w[4*k] * uv.x + w[4*k+1] * uv.y + w[4*k+2] * uv.z + w[4*k+3] * uv.w;
        }
        proj[(size_t)(t0 + tt) * R_DIM + r] = acc;   // coalesced per tt
    }
}

// ---------------- device-wide spin barrier (monotonic counter) ---------------
// Residency is guaranteed by hipLaunchCooperativeKernel, so spinning is safe.
__device__ __forceinline__ void gbar(unsigned int* cnt, unsigned int target)
{
    __syncthreads();   // drains this block's vmem stores (s_waitcnt before s_barrier)
    if (threadIdx.x == 0) {
        // agent-scope release RMW: buffer_wbl2 -> our x-slice reaches L3
        __hip_atomic_fetch_add(cnt, 1u, __ATOMIC_RELEASE, __HIP_MEMORY_SCOPE_AGENT);
        while (__hip_atomic_load(cnt, __ATOMIC_RELAXED, __HIP_MEMORY_SCOPE_AGENT) < target)
            __builtin_amdgcn_s_sleep(1);
        // agent-scope acquire: buffer_inv -> subsequent plain x loads are fresh
        (void)__hip_atomic_load(cnt, __ATOMIC_ACQUIRE, __HIP_MEMORY_SCOPE_AGENT);
    }
    __syncthreads();
}

// ---------------- persistent recurrence kernel -------------------------------
// 256 blocks x 256 threads (cooperative: co-residency guaranteed). Block owns
// 8 rows of Wres, held entirely in VGPRs (64 floats/thread). proj is staged in
// `out` and overwritten in place with x_t.
__global__ __launch_bounds__(256) void esn_recur_kernel(
    const float* __restrict__ Wres, float* __restrict__ out,
    float* __restrict__ xbuf, unsigned int* cnt)
{
    const int tid   = threadIdx.x;
    const int row_l = tid >> 5;          // 0..7  : local row
    const int seg   = tid & 31;          // 0..31 : 64-col segment of that row
    const int r     = blockIdx.x * ROWS_PER_BLK + row_l;

    // W fragment: W[r][seg*64 .. seg*64+63] -> 64 VGPRs
    float w[64];
    const float4* wrow = (const float4*)(Wres + (size_t)r * R_DIM + seg * 64);
#pragma unroll
    for (int k = 0; k < 16; ++k) {
        float4 v = wrow[k];
        w[4*k] = v.x; w[4*k+1] = v.y; w[4*k+2] = v.z; w[4*k+3] = v.w;
    }

    __shared__ float xs[R_DIM + (R_DIM / 64) * 4];   // 8704 B, padded

    // step 0: x0 = tanh(proj[0]) (no leak, no Wres term)
    float xcur = 0.f;
    if (seg == 0) {
        xcur = tanhf(out[r]);
        xbuf[r] = xcur;        // buffer 0
        out[r]  = xcur;
    }

    for (int t = 1; t < T_STEPS; ++t) {
        // prefetch proj[t][r] BEFORE the barrier (doesn't depend on x;
        // read-only since kernel start, so no coherence hazard)
        float p = 0.f;
        if (seg == 0) p = out[(size_t)t * R_DIM + r];

        gbar(cnt, (unsigned int)t * G_BLK);          // x_{t-1} now globally visible

        // stage full x_{t-1} (8 KB) into LDS, padded layout
        const float4* xp = (const float4*)(xbuf + ((t - 1) & 1) * R_DIM);
#pragma unroll
        for (int i = 0; i < 2; ++i) {
            int q = tid + 256 * i;
            float4 v = xp[q];
            *(float4*)&xs[xidx(4 * q)] = v;
        }
        __syncthreads();

        // 64 FMAs against register-resident W
        const float* xseg = xs + xidx(seg * 64);
        float acc = 0.f;
#pragma unroll
        for (int k = 0; k < 16; ++k) {
            float4 xv = *(const float4*)(xseg + 4 * k);
            acc += w[4*k] * xv.x + w[4*k+1] * xv.y + w[4*k+2] * xv.z + w[4*k+3] * xv.w;
        }
        // reduce 32 segments -> row dot product (lanes 0 and 32 hold sums;
        // masks 16..1 stay within each 32-lane half of the wave64)
        acc += __shfl_xor(acc, 16);
        acc += __shfl_xor(acc, 8);
        acc += __shfl_xor(acc, 4);
        acc += __shfl_xor(acc, 2);
        acc += __shfl_xor(acc, 1);

        if (seg == 0) {
            float xi = tanhf(p + acc);
            float xn = (1.f - LR) * xcur + LR * xi;
            xcur = xn;                                  // row state stays in-register
            xbuf[(t & 1) * R_DIM + r] = xn;
            out[(size_t)t * R_DIM + r] = xn;
        }
        // no trailing sync needed: gbar at top of next iter starts with __syncthreads
    }
}

extern "C" void kernel_launch(void* const* d_in, const int* in_sizes, int n_in,
                              void* d_out, int out_size, void* d_ws, size_t ws_size,
                              hipStream_t stream)
{
    const float* u    = (const float*)d_in[0];   // [8192, 64]
    const float* Winw = (const float*)d_in[1];   // [2048, 64]
    const float* Winb = (const float*)d_in[2];   // [2048]
    const float* Wres = (const float*)d_in[3];   // [2048, 2048]
    float* out = (float*)d_out;                  // [8192, 2048]

    float* xbuf = (float*)d_ws;                                   // 2 x 2048 floats
    unsigned int* cnt = (unsigned int*)((char*)d_ws + 2 * R_DIM * sizeof(float));

    hipMemsetAsync(cnt, 0, sizeof(unsigned int), stream);         // capture-legal

    dim3 pgrid(T_STEPS / 64, R_DIM / 256);
    esn_proj_kernel<<<pgrid, 256, 0, stream>>>(u, Winw, Winb, out);

    // Cooperative launch: co-residency of all 256 blocks guaranteed (or the
    // launch errors out) -> the spin barrier cannot deadlock.
    const float* WresArg = Wres;
    float* outArg  = out;
    float* xbufArg = xbuf;
    unsigned int* cntArg = cnt;
    void* args[] = { (void*)&WresArg, (void*)&outArg, (void*)&xbufArg, (void*)&cntArg };
    hipLaunchCooperativeKernel((void*)esn_recur_kernel, dim3(G_BLK), dim3(256),
                               args, 0, stream);
}